// Round 6
// baseline (131.605 us; speedup 1.0000x reference)
//
#include <hip/hip_runtime.h>

#define NX 352
#define NY 256
#define NZ 64

__device__ __forceinline__ float rcpf(float x) { return __builtin_amdgcn_rcpf(x); }

__device__ __forceinline__ float limiter(float cr) {
    return fmaxf(0.f, fmaxf(fminf(1.f, 2.f * cr), fminf(2.f, cr)));
}

__device__ __forceinline__ float sbflux(float vm1, float v0, float vp1, float vp2,
                                        float mm1, float m0, float mp1,
                                        float vel, float velfac, float rinv_dx)
{
    float rjp = (vp2 - vp1) * mp1;
    float rj  = (vp1 - v0) * m0;
    float rjm = (v0 - vm1) * mm1;
    float fv = velfac * vel;
    float uCFL = fabsf(fv * rinv_dx);
    float rden = (fabsf(rj) < 1e-20f) ? 1e-20f : rj;
    float cr = limiter(((vel > 0.f) ? rjm : rjp) * rcpf(rden));
    return fv * (vp1 + v0) * 0.5f - fabsf(fv) * ((1.f - cr) + uCFL * cr) * rj * 0.5f;
}

__device__ __forceinline__ float zflux(float t, float mw, float wv, int lane, float inv_dzwk)
{
    float t_km1 = __shfl_up(t, 1),  t_kp1 = __shfl_down(t, 1),  t_kp2 = __shfl_down(t, 2);
    float m_km1 = __shfl_up(mw, 1), m_kp1 = __shfl_down(mw, 1), m_kp2 = __shfl_down(mw, 2);
    float mm1 = (lane >= 1) ? mw * m_km1 : 0.f;
    float m0  = m_kp1 * mw;
    float mp1 = (lane + 1 < NZ - 1) ? m_kp2 * m_kp1 : 0.f;
    return sbflux(t_km1, t, t_kp1, t_kp2, mm1, m0, mp1, wv, 1.f, inv_dzwk);
}

__device__ __forceinline__ float vertdiv(float ft, int lane, float inv_dzwk, float inv_dzw_last)
{
    float ftm1 = __shfl_up(ft, 1);
    if (lane == 0) return -ft * inv_dzwk;
    if (lane < NZ - 1) return -(ft - ftm1) * inv_dzwk;
    return ftm1 * inv_dzw_last;
}

__device__ __forceinline__ void tri_setup(float tk_tau, float kap, float mx, float fo,
                                          float fs, int ks, bool interior, int lane,
                                          float inv_dzwk, float inv_dzw_last, float inv_dzt_p,
                                          float &A, float &C, float &D, bool &water)
{
    float kp = __shfl_down(kap, 1);
    float delta = (lane < NZ - 1) ? 0.5f * (kap + kp) * inv_dzt_p : 0.f;
    float dm = __shfl_up(delta, 1); if (lane == 0) dm = 0.f;
    float diss = 0.7f * sqrtf(fmaxf(0.f, tk_tau)) * rcpf(mx);
    float a, b;
    if (lane == 0)          { a = 0.f; b = 0.f; }
    else if (lane < NZ - 1) { a = -dm * inv_dzwk; b = 1.f + (delta + dm) * inv_dzwk + diss; }
    else                    { a = -dm * inv_dzw_last; b = 1.f + dm * inv_dzw_last + diss; }
    float bE = 1.f + delta * inv_dzwk + diss;
    float c  = (lane < NZ - 1) ? -delta * inv_dzwk : 0.f;
    float d  = tk_tau + fo;
    if (lane == NZ - 1) d += fs * inv_dzw_last;
    bool land = interior && (ks >= 0);
    water = land && (lane >= ks);
    bool edge = land && (lane == ks);
    float At = (water && !edge) ? a : 0.f;
    float Bt = edge ? bE : (water ? b : 1.f);
    float Ct = water ? c : 0.f;
    float Dt = water ? d : 0.f;
    float r = rcpf(Bt);
    A = At * r; C = Ct * r; D = Dt * r;
}

__device__ __forceinline__ void pcr_step(float &A, float &C, float &D, int s, bool lo, bool hi)
{
    float am = __shfl_up(A, s),   cm = __shfl_up(C, s),   dm = __shfl_up(D, s);
    float ap = __shfl_down(A, s), cp = __shfl_down(C, s), dp = __shfl_down(D, s);
    if (lo) { am = 0.f; cm = 0.f; dm = 0.f; }
    if (hi) { ap = 0.f; cp = 0.f; dp = 0.f; }
    float r = rcpf(1.f - A * cm - C * ap);
    float nA = -A * am * r, nC = -C * cp * r;
    float nD = (D - A * dm - C * dp) * r;
    A = nA; C = nC; D = nD;
}

__global__ __launch_bounds__(256) void
tke_fused(const float* __restrict__ tke, const float* __restrict__ dtke,
          const float* __restrict__ u, const float* __restrict__ v,
          const float* __restrict__ w,
          const float* __restrict__ maskU, const float* __restrict__ maskV,
          const float* __restrict__ maskW,
          const float* __restrict__ kappaM, const float* __restrict__ mxl,
          const float* __restrict__ forc, const float* __restrict__ forc_surf,
          const int* __restrict__ kbot,
          const float* __restrict__ dxt, const float* __restrict__ dxu,
          const float* __restrict__ dyt, const float* __restrict__ dyu,
          const float* __restrict__ dzt, const float* __restrict__ dzw,
          const float* __restrict__ cost, const float* __restrict__ cosu,
          float* __restrict__ out_tke, float* __restrict__ out_dtke,
          float* __restrict__ out_corr)
{
    const int lane = threadIdx.x;                       // k, 0..63
    // XCD-aware swizzle: 5632 blocks = 8 * 704 (bijective)
    int bid = blockIdx.x;
    bid = (bid & 7) * 704 + (bid >> 3);
    const int qid = bid * 4 + threadIdx.y;              // quad id over (NX/2, NY/2)
    const int qi = qid >> 7;                            // NY/2 = 128
    const int qj = qid & 127;
    const int i0 = qi << 1, j0 = qj << 1;
    const bool interior = (i0 >= 2 && i0 < NX - 2 && j0 >= 2 && j0 < NY - 2);

    const unsigned SX = (unsigned)NY * NZ;
    const unsigned c00 = (unsigned)(i0 * NY + j0);
    const unsigned p00 = c00 * NZ + lane;
    const unsigned p01 = p00 + NZ;
    const unsigned p10 = p00 + SX;
    const unsigned p11 = p10 + NZ;
    const unsigned ox = interior ? SX : 0u;
    const unsigned oy = interior ? (unsigned)NZ : 0u;
    const int im = interior ? i0 - 1 : i0;
    const int jm = interior ? j0 - 1 : j0;

    // ---------------- loads ----------------
    const float3 tk00 = *(const float3*)(tke + 3u * p00);
    const float3 tk01 = *(const float3*)(tke + 3u * p01);
    const float3 tk10 = *(const float3*)(tke + 3u * p10);
    const float3 tk11 = *(const float3*)(tke + 3u * p11);
    const float3 dt00 = *(const float3*)(dtke + 3u * p00);
    const float3 dt01 = *(const float3*)(dtke + 3u * p01);
    const float3 dt10 = *(const float3*)(dtke + 3u * p10);
    const float3 dt11 = *(const float3*)(dtke + 3u * p11);

    const float mw00 = maskW[p00], mw01 = maskW[p01], mw10 = maskW[p10], mw11 = maskW[p11];

    // x-plane stencil (row 0 = j0, row 1 = j0+1)
    const float tx_m2_0 = tke[3u * (p00 - 2u * ox)], tx_m1_0 = tke[3u * (p00 - ox)];
    const float tx_p2_0 = tke[3u * (p10 + ox)],      tx_p3_0 = tke[3u * (p10 + 2u * ox)];
    const float mx_m2_0 = maskW[p00 - 2u * ox], mx_m1_0 = maskW[p00 - ox];
    const float mx_p2_0 = maskW[p10 + ox],      mx_p3_0 = maskW[p10 + 2u * ox];
    const float tx_m2_1 = tke[3u * (p01 - 2u * ox)], tx_m1_1 = tke[3u * (p01 - ox)];
    const float tx_p2_1 = tke[3u * (p11 + ox)],      tx_p3_1 = tke[3u * (p11 + 2u * ox)];
    const float mx_m2_1 = maskW[p01 - 2u * ox], mx_m1_1 = maskW[p01 - ox];
    const float mx_p2_1 = maskW[p11 + ox],      mx_p3_1 = maskW[p11 + 2u * ox];

    // y-plane stencil (row A = i0, row B = i0+1)
    const float ty_m2_A = tke[3u * (p00 - 2u * oy)], ty_m1_A = tke[3u * (p00 - oy)];
    const float ty_p2_A = tke[3u * (p01 + oy)],      ty_p3_A = tke[3u * (p01 + 2u * oy)];
    const float my_m2_A = maskW[p00 - 2u * oy], my_m1_A = maskW[p00 - oy];
    const float my_p2_A = maskW[p01 + oy],      my_p3_A = maskW[p01 + 2u * oy];
    const float ty_m2_B = tke[3u * (p10 - 2u * oy)], ty_m1_B = tke[3u * (p10 - oy)];
    const float ty_p2_B = tke[3u * (p11 + oy)],      ty_p3_B = tke[3u * (p11 + 2u * oy)];
    const float my_m2_B = maskW[p10 - 2u * oy], my_m1_B = maskW[p10 - oy];
    const float my_p2_B = maskW[p11 + oy],      my_p3_B = maskW[p11 + 2u * oy];

    // velocities + face masks
    const float u_m_0 = u[3u * (p00 - ox)], u_0_0 = u[3u * p00], u_1_0 = u[3u * p10];
    const float u_m_1 = u[3u * (p01 - ox)], u_0_1 = u[3u * p01], u_1_1 = u[3u * p11];
    const float v_m_A = v[3u * (p00 - oy)], v_0_A = v[3u * p00], v_1_A = v[3u * p01];
    const float v_m_B = v[3u * (p10 - oy)], v_0_B = v[3u * p10], v_1_B = v[3u * p11];
    const float w00 = w[3u * p00], w01 = w[3u * p01], w10 = w[3u * p10], w11 = w[3u * p11];
    const float mU_m_0 = maskU[p00 - ox], mU_0_0 = maskU[p00], mU_1_0 = maskU[p10];
    const float mU_m_1 = maskU[p01 - ox], mU_0_1 = maskU[p01], mU_1_1 = maskU[p11];
    const float mV_m_A = maskV[p00 - oy], mV_0_A = maskV[p00], mV_1_A = maskV[p01];
    const float mV_m_B = maskV[p10 - oy], mV_0_B = maskV[p10], mV_1_B = maskV[p11];

    // tridiag inputs
    const float ka00 = kappaM[p00], ka01 = kappaM[p01], ka10 = kappaM[p10], ka11 = kappaM[p11];
    const float ml00 = mxl[p00], ml01 = mxl[p01], ml10 = mxl[p10], ml11 = mxl[p11];
    const float fo00 = forc[p00], fo01 = forc[p01], fo10 = forc[p10], fo11 = forc[p11];
    const int ks00 = kbot[c00] - 1,      ks01 = kbot[c00 + 1] - 1;
    const int ks10 = kbot[c00 + NY] - 1, ks11 = kbot[c00 + NY + 1] - 1;
    const float fs00 = forc_surf[c00],      fs01 = forc_surf[c00 + 1];
    const float fs10 = forc_surf[c00 + NY], fs11 = forc_surf[c00 + NY + 1];

    // lane constants
    const float dzwk         = dzw[lane];
    const float inv_dzwk     = rcpf(dzwk);
    const float dzw_last     = 0.5f * dzw[NZ - 1];
    const float inv_dzw_last = rcpf(dzw_last);
    const float inv_dzt_p    = rcpf(dzt[(lane < NZ - 1) ? lane + 1 : NZ - 1]);

    // geometry factors
    const float cj0 = cost[j0], cj1 = cost[j0 + 1], cjm = cost[jm];
    const float cu_m = cosu[jm], cu_0 = cosu[j0], cu_1 = cosu[j0 + 1];
    const float dxt_m = dxt[im], dxt_0 = dxt[i0], dxt_1 = dxt[i0 + 1];
    const float dxu_m = dxu[im], dxu_0 = dxu[i0], dxu_1 = dxu[i0 + 1];
    const float dyt_m = dyt[jm], dyt_0 = dyt[j0], dyt_1 = dyt[j0 + 1];
    const float dyu_m = dyu[jm], dyu_0 = dyu[j0], dyu_1 = dyu[j0 + 1];

    const float rdxm_0 = rcpf(cj0 * dxt_m), rdx0_0 = rcpf(cj0 * dxt_0), rdx1_0 = rcpf(cj0 * dxt_1);
    const float rdxm_1 = rcpf(cj1 * dxt_m), rdx0_1 = rcpf(cj1 * dxt_0), rdx1_1 = rcpf(cj1 * dxt_1);
    const float rdy_m = rcpf(cjm * dyt_m), rdy_0 = rcpf(cj0 * dyt_0), rdy_1 = rcpf(cj1 * dyt_1);
    const float rdxu_m_0 = rcpf(cj0 * dxu_m), rdxu_0_0 = rcpf(cj0 * dxu_0), rdxu_1_0 = rcpf(cj0 * dxu_1);
    const float rdxu_m_1 = rcpf(cj1 * dxu_m), rdxu_0_1 = rcpf(cj1 * dxu_0), rdxu_1_1 = rcpf(cj1 * dxu_1);
    const float cud_m = cu_m * rcpf(dyu_m), cud_0 = cu_0 * rcpf(dyu_0), cud_1 = cu_1 * rcpf(dyu_1);

    // ---------------- x advection (3 interfaces per j-row, middle shared) ----------------
    const float q_m2_0 = mx_m1_0 * mx_m2_0, q_m1_0 = mw00 * mx_m1_0, q_0_0 = mw10 * mw00;
    const float q_p1_0 = mx_p2_0 * mw10,    q_p2_0 = mx_p3_0 * mx_p2_0;
    float feM_0 = sbflux(tx_m2_0, tx_m1_0, tk00.x, tk10.x, q_m2_0, q_m1_0, q_0_0, u_m_0, 1.f, rdxm_0);
    float feS_0 = sbflux(tx_m1_0, tk00.x, tk10.x, tx_p2_0, q_m1_0, q_0_0, q_p1_0, u_0_0, 1.f, rdx0_0);
    float feP_0 = sbflux(tk00.x, tk10.x, tx_p2_0, tx_p3_0, q_0_0, q_p1_0, q_p2_0, u_1_0, 1.f, rdx1_0);

    const float q_m2_1 = mx_m1_1 * mx_m2_1, q_m1_1 = mw01 * mx_m1_1, q_0_1 = mw11 * mw01;
    const float q_p1_1 = mx_p2_1 * mw11,    q_p2_1 = mx_p3_1 * mx_p2_1;
    float feM_1 = sbflux(tx_m2_1, tx_m1_1, tk01.x, tk11.x, q_m2_1, q_m1_1, q_0_1, u_m_1, 1.f, rdxm_1);
    float feS_1 = sbflux(tx_m1_1, tk01.x, tk11.x, tx_p2_1, q_m1_1, q_0_1, q_p1_1, u_0_1, 1.f, rdx0_1);
    float feP_1 = sbflux(tk01.x, tk11.x, tx_p2_1, tx_p3_1, q_0_1, q_p1_1, q_p2_1, u_1_1, 1.f, rdx1_1);

    // ---------------- y advection (3 interfaces per i-row, middle shared) ----------------
    const float r_m2_A = my_m1_A * my_m2_A, r_m1_A = mw00 * my_m1_A, r_0_A = mw01 * mw00;
    const float r_p1_A = my_p2_A * mw01,    r_p2_A = my_p3_A * my_p2_A;
    float fnM_A = sbflux(ty_m2_A, ty_m1_A, tk00.x, tk01.x, r_m2_A, r_m1_A, r_0_A, v_m_A, cu_m, rdy_m);
    float fnS_A = sbflux(ty_m1_A, tk00.x, tk01.x, ty_p2_A, r_m1_A, r_0_A, r_p1_A, v_0_A, cu_0, rdy_0);
    float fnP_A = sbflux(tk00.x, tk01.x, ty_p2_A, ty_p3_A, r_0_A, r_p1_A, r_p2_A, v_1_A, cu_1, rdy_1);

    const float r_m2_B = my_m1_B * my_m2_B, r_m1_B = mw10 * my_m1_B, r_0_B = mw11 * mw10;
    const float r_p1_B = my_p2_B * mw11,    r_p2_B = my_p3_B * my_p2_B;
    float fnM_B = sbflux(ty_m2_B, ty_m1_B, tk10.x, tk11.x, r_m2_B, r_m1_B, r_0_B, v_m_B, cu_m, rdy_m);
    float fnS_B = sbflux(ty_m1_B, tk10.x, tk11.x, ty_p2_B, r_m1_B, r_0_B, r_p1_B, v_0_B, cu_0, rdy_0);
    float fnP_B = sbflux(tk10.x, tk11.x, ty_p2_B, ty_p3_B, r_0_B, r_p1_B, r_p2_B, v_1_B, cu_1, rdy_1);

    // ---------------- z advection per column ----------------
    float vert00 = vertdiv(zflux(tk00.x, mw00, w00, lane, inv_dzwk), lane, inv_dzwk, inv_dzw_last);
    float vert01 = vertdiv(zflux(tk01.x, mw01, w01, lane, inv_dzwk), lane, inv_dzwk, inv_dzw_last);
    float vert10 = vertdiv(zflux(tk10.x, mw10, w10, lane, inv_dzwk), lane, inv_dzwk, inv_dzw_last);
    float vert11 = vertdiv(zflux(tk11.x, mw11, w11, lane, inv_dzwk), lane, inv_dzwk, inv_dzw_last);

    float hor00 = mw00 * (-(feS_0 - feM_0) * rdx0_0 - (fnS_A - fnM_A) * rdy_0);
    float hor10 = mw10 * (-(feP_0 - feS_0) * rdx1_0 - (fnS_B - fnM_B) * rdy_0);
    float hor01 = mw01 * (-(feS_1 - feM_1) * rdx0_1 - (fnP_A - fnS_A) * rdy_1);
    float hor11 = mw11 * (-(feP_1 - feS_1) * rdx1_1 - (fnP_B - fnS_B) * rdy_1);

    // ---------------- horizontal diffusion ----------------
    float fd_m_0 = 2000.f * (tk00.x - tx_m1_0) * rdxu_m_0 * mU_m_0;
    float fd_0_0 = 2000.f * (tk10.x - tk00.x)  * rdxu_0_0 * mU_0_0;
    float fd_p_0 = 2000.f * (tx_p2_0 - tk10.x) * rdxu_1_0 * mU_1_0;
    float fd_m_1 = 2000.f * (tk01.x - tx_m1_1) * rdxu_m_1 * mU_m_1;
    float fd_0_1 = 2000.f * (tk11.x - tk01.x)  * rdxu_0_1 * mU_0_1;
    float fd_p_1 = 2000.f * (tx_p2_1 - tk11.x) * rdxu_1_1 * mU_1_1;
    float fg_m_A = 2000.f * (tk00.x - ty_m1_A) * cud_m * mV_m_A;
    float fg_0_A = 2000.f * (tk01.x - tk00.x)  * cud_0 * mV_0_A;
    float fg_p_A = 2000.f * (ty_p2_A - tk01.x) * cud_1 * mV_1_A;
    float fg_m_B = 2000.f * (tk10.x - ty_m1_B) * cud_m * mV_m_B;
    float fg_0_B = 2000.f * (tk11.x - tk10.x)  * cud_0 * mV_0_B;
    float fg_p_B = 2000.f * (ty_p2_B - tk11.x) * cud_1 * mV_1_B;

    float diff00 = interior ? mw00 * ((fd_0_0 - fd_m_0) * rdx0_0 + (fg_0_A - fg_m_A) * rdy_0) : 0.f;
    float diff10 = interior ? mw10 * ((fd_p_0 - fd_0_0) * rdx1_0 + (fg_0_B - fg_m_B) * rdy_0) : 0.f;
    float diff01 = interior ? mw01 * ((fd_0_1 - fd_m_1) * rdx0_1 + (fg_p_A - fg_0_A) * rdy_1) : 0.f;
    float diff11 = interior ? mw11 * ((fd_p_1 - fd_0_1) * rdx1_1 + (fg_p_B - fg_0_B) * rdy_1) : 0.f;

    const float dtk00 = interior ? (hor00 + vert00) : dt00.x;
    const float dtk01 = interior ? (hor01 + vert01) : dt01.x;
    const float dtk10 = interior ? (hor10 + vert10) : dt10.x;
    const float dtk11 = interior ? (hor11 + vert11) : dt11.x;

    // store out_dtke now to shrink the live set across PCR
    float3 od;
    od.x = dtk00; od.y = dt00.y; od.z = dt00.z; *(float3*)(out_dtke + 3u * p00) = od;
    od.x = dtk01; od.y = dt01.y; od.z = dt01.z; *(float3*)(out_dtke + 3u * p01) = od;
    od.x = dtk10; od.y = dt10.y; od.z = dt10.z; *(float3*)(out_dtke + 3u * p10) = od;
    od.x = dtk11; od.y = dt11.y; od.z = dt11.z; *(float3*)(out_dtke + 3u * p11) = od;

    // AB terms folded: out_tke.y = partial + rest
    const float rest00 = diff00 + 1.6f * dtk00 - 0.6f * dt00.z;
    const float rest01 = diff01 + 1.6f * dtk01 - 0.6f * dt01.z;
    const float rest10 = diff10 + 1.6f * dtk10 - 0.6f * dt10.z;
    const float rest11 = diff11 + 1.6f * dtk11 - 0.6f * dt11.z;

    // ---------------- tridiag setup + 4-chain PCR ----------------
    float A00, C00, D00, A01, C01, D01, A10, C10, D10, A11, C11, D11;
    bool w00b, w01b, w10b, w11b;
    tri_setup(tk00.x, ka00, ml00, fo00, fs00, ks00, interior, lane,
              inv_dzwk, inv_dzw_last, inv_dzt_p, A00, C00, D00, w00b);
    tri_setup(tk01.x, ka01, ml01, fo01, fs01, ks01, interior, lane,
              inv_dzwk, inv_dzw_last, inv_dzt_p, A01, C01, D01, w01b);
    tri_setup(tk10.x, ka10, ml10, fo10, fs10, ks10, interior, lane,
              inv_dzwk, inv_dzw_last, inv_dzt_p, A10, C10, D10, w10b);
    tri_setup(tk11.x, ka11, ml11, fo11, fs11, ks11, interior, lane,
              inv_dzwk, inv_dzw_last, inv_dzt_p, A11, C11, D11, w11b);

    #pragma unroll
    for (int s = 1; s < NZ; s <<= 1) {
        const bool lo = (lane < s);
        const bool hi = (lane + s >= NZ);
        pcr_step(A00, C00, D00, s, lo, hi);
        pcr_step(A01, C01, D01, s, lo, hi);
        pcr_step(A10, C10, D10, s, lo, hi);
        pcr_step(A11, C11, D11, s, lo, hi);
    }

    float pa00 = w00b ? D00 : tk00.y;
    float pa01 = w01b ? D01 : tk01.y;
    float pa10 = w10b ? D10 : tk10.y;
    float pa11 = w11b ? D11 : tk11.y;

    if (lane == NZ - 1) {
        float c0 = 0.f, c1 = 0.f, c2 = 0.f, c3 = 0.f;
        if (interior) {
            if (pa00 < 0.f) { c0 = -pa00 * dzw_last; pa00 = 0.f; }
            if (pa01 < 0.f) { c1 = -pa01 * dzw_last; pa01 = 0.f; }
            if (pa10 < 0.f) { c2 = -pa10 * dzw_last; pa10 = 0.f; }
            if (pa11 < 0.f) { c3 = -pa11 * dzw_last; pa11 = 0.f; }
        }
        out_corr[c00] = c0;      out_corr[c00 + 1] = c1;
        out_corr[c00 + NY] = c2; out_corr[c00 + NY + 1] = c3;
    }

    // ---------------- final dense stores ----------------
    float3 ot;
    ot.x = tk00.x; ot.y = pa00 + rest00; ot.z = tk00.z; *(float3*)(out_tke + 3u * p00) = ot;
    ot.x = tk01.x; ot.y = pa01 + rest01; ot.z = tk01.z; *(float3*)(out_tke + 3u * p01) = ot;
    ot.x = tk10.x; ot.y = pa10 + rest10; ot.z = tk10.z; *(float3*)(out_tke + 3u * p10) = ot;
    ot.x = tk11.x; ot.y = pa11 + rest11; ot.z = tk11.z; *(float3*)(out_tke + 3u * p11) = ot;
}

extern "C" void kernel_launch(void* const* d_in, const int* in_sizes, int n_in,
                              void* d_out, int out_size, void* d_ws, size_t ws_size,
                              hipStream_t stream)
{
    const float* u         = (const float*)d_in[0];
    const float* v         = (const float*)d_in[1];
    const float* w         = (const float*)d_in[2];
    const float* maskU     = (const float*)d_in[3];
    const float* maskV     = (const float*)d_in[4];
    const float* maskW     = (const float*)d_in[5];
    const float* dxt       = (const float*)d_in[6];
    const float* dxu       = (const float*)d_in[7];
    const float* dyt       = (const float*)d_in[8];
    const float* dyu       = (const float*)d_in[9];
    const float* dzt       = (const float*)d_in[10];
    const float* dzw       = (const float*)d_in[11];
    const float* cost      = (const float*)d_in[12];
    const float* cosu      = (const float*)d_in[13];
    const int*   kbot      = (const int*)d_in[14];
    const float* kappaM    = (const float*)d_in[15];
    const float* mxl       = (const float*)d_in[16];
    const float* forc      = (const float*)d_in[17];
    const float* forc_surf = (const float*)d_in[18];
    const float* tke       = (const float*)d_in[19];
    const float* dtke      = (const float*)d_in[20];

    float* out_tke  = (float*)d_out;
    float* out_dtke = out_tke + (size_t)NX * NY * NZ * 3;
    float* out_corr = out_dtke + (size_t)NX * NY * NZ * 3;

    // (NX/2)*(NY/2) quads, 4 quads (waves) per block -> 5632 blocks
    tke_fused<<<dim3((NX / 2) * (NY / 2) / 4), dim3(64, 4), 0, stream>>>(
        tke, dtke, u, v, w, maskU, maskV, maskW,
        kappaM, mxl, forc, forc_surf, kbot,
        dxt, dxu, dyt, dyu, dzt, dzw, cost, cosu,
        out_tke, out_dtke, out_corr);
}